// Round 1
// baseline (763.951 us; speedup 1.0000x reference)
//
#include <hip/hip_runtime.h>

// Problem constants
#define B_    16
#define DIM   128
#define NPTS  16384
#define J_    16
#define K_    128
#define L_    128
#define R_    8
#define M1_   64

// Workspace layout (in floats)
#define OFF_XHAT 0                         // [2048][128]
#define OFF_HT   (2048*128)                // Ht[j][l][k]  [16][128][128]
#define OFF_WT   (2*2048*128)              // Wt[j][i][o]  [16][128][128]
#define OFF_T    (3*2048*128)              // T[b][j][i][k] [16][16][128][128]
#define OFF_Y    (3*2048*128 + 16*16*128*128) // y[b][o][k] [16][128][128]

// ---------------------------------------------------------------------------
// prep: Ht[j][l][k] = D_out[j,k]*D_in[j,l]*product[k,l] + (k<64&&l<64)?Q[j,k,l]:0
//       Wt[j][i][o] = weights[i][o][j]
// grid 4096 x 128 threads
__global__ __launch_bounds__(128) void k_prep(
    const float* __restrict__ product, const float* __restrict__ Do,
    const float* __restrict__ Di, const float* __restrict__ A,
    const float* __restrict__ Bm, const float* __restrict__ W,
    float* __restrict__ Ht, float* __restrict__ Wt)
{
    int bid = blockIdx.x;
    if (bid < 2048) {
        int j = bid >> 7, l = bid & 127, k = threadIdx.x;
        float v = Do[j*K_ + k] * Di[j*L_ + l] * product[k*L_ + l];
        if (k < M1_ && l < M1_) {
            float q = 0.f;
            #pragma unroll
            for (int r = 0; r < R_; ++r)
                q += A[(j*R_ + r)*M1_ + k] * Bm[(j*R_ + r)*M1_ + l];
            v += q;
        }
        Ht[((size_t)j*L_ + l)*K_ + k] = v;
    } else {
        int b2 = bid - 2048;
        int j = b2 >> 7, i = b2 & 127, o = threadIdx.x;
        Wt[((size_t)j*DIM + i)*DIM + o] = W[((size_t)i*DIM + o)*J_ + j];
    }
}

// ---------------------------------------------------------------------------
// x_hat[bc][l] += sum_p x[bc][p]*wbases[p][l]   (K-split over blockIdx.y)
// grid (16, 32), 256 threads, 128x128 tile, K-chunk 512
__global__ __launch_bounds__(256) void k_xhat(
    const float* __restrict__ x, const float* __restrict__ wbases,
    float* __restrict__ xhat)
{
    __shared__ float sA[32][132];  // [p][bc_row]
    __shared__ float sB[32][132];  // [p][l]
    const int t = threadIdx.x;
    const int tx = t & 15, ty = t >> 4;
    const int bc0 = blockIdx.x * 128;
    const int p0  = blockIdx.y * 512;

    float acc[8][8];
    #pragma unroll
    for (int m = 0; m < 8; ++m)
        #pragma unroll
        for (int n = 0; n < 8; ++n) acc[m][n] = 0.f;

    for (int pc = 0; pc < 512; pc += 32) {
        #pragma unroll
        for (int it = 0; it < 4; ++it) {   // x tile: 128 rows x 32 p, transpose
            int idx = t + it*256;
            int row = idx >> 3, col = (idx & 7) << 2;
            float4 v = *(const float4*)(x + (size_t)(bc0+row)*NPTS + p0 + pc + col);
            sA[col+0][row] = v.x; sA[col+1][row] = v.y;
            sA[col+2][row] = v.z; sA[col+3][row] = v.w;
        }
        #pragma unroll
        for (int it = 0; it < 4; ++it) {   // wbases tile: 32 p x 128 l, direct
            int idx = t + it*256;
            int row = idx >> 5, col = (idx & 31) << 2;
            *(float4*)&sB[row][col] =
                *(const float4*)(wbases + (size_t)(p0+pc+row)*L_ + col);
        }
        __syncthreads();
        #pragma unroll
        for (int k = 0; k < 32; ++k) {
            float a[8], b[8];
            *(float4*)&a[0] = *(const float4*)&sA[k][ty*8];
            *(float4*)&a[4] = *(const float4*)&sA[k][ty*8+4];
            *(float4*)&b[0] = *(const float4*)&sB[k][tx*8];
            *(float4*)&b[4] = *(const float4*)&sB[k][tx*8+4];
            #pragma unroll
            for (int m = 0; m < 8; ++m)
                #pragma unroll
                for (int n = 0; n < 8; ++n) acc[m][n] += a[m]*b[n];
        }
        __syncthreads();
    }
    #pragma unroll
    for (int m = 0; m < 8; ++m) {
        int row = bc0 + ty*8 + m;
        #pragma unroll
        for (int n = 0; n < 8; ++n)
            atomicAdd(&xhat[(size_t)row*L_ + tx*8 + n], acc[m][n]);
    }
}

// ---------------------------------------------------------------------------
// T[b][j][i][k] = sum_l xhat[b][i][l] * Ht[j][l][k]
// grid (16 b, 16 j), 256 threads
__global__ __launch_bounds__(256) void k_mix1(
    const float* __restrict__ xhat, const float* __restrict__ Ht,
    float* __restrict__ T)
{
    __shared__ float sA[32][132];  // [l][i]
    __shared__ float sB[32][132];  // [l][k]
    const int t = threadIdx.x;
    const int tx = t & 15, ty = t >> 4;
    const int b = blockIdx.x, j = blockIdx.y;
    const float* xb = xhat + (size_t)b*DIM*L_;
    const float* hj = Ht + (size_t)j*L_*K_;

    float acc[8][8];
    #pragma unroll
    for (int m = 0; m < 8; ++m)
        #pragma unroll
        for (int n = 0; n < 8; ++n) acc[m][n] = 0.f;

    for (int l0 = 0; l0 < L_; l0 += 32) {
        #pragma unroll
        for (int it = 0; it < 4; ++it) {   // xhat: 128 i x 32 l, transpose
            int idx = t + it*256;
            int row = idx >> 3, col = (idx & 7) << 2;
            float4 v = *(const float4*)(xb + (size_t)row*L_ + l0 + col);
            sA[col+0][row] = v.x; sA[col+1][row] = v.y;
            sA[col+2][row] = v.z; sA[col+3][row] = v.w;
        }
        #pragma unroll
        for (int it = 0; it < 4; ++it) {   // Ht: 32 l x 128 k, direct
            int idx = t + it*256;
            int row = idx >> 5, col = (idx & 31) << 2;
            *(float4*)&sB[row][col] =
                *(const float4*)(hj + (size_t)(l0+row)*K_ + col);
        }
        __syncthreads();
        #pragma unroll
        for (int k = 0; k < 32; ++k) {
            float a[8], b[8];
            *(float4*)&a[0] = *(const float4*)&sA[k][ty*8];
            *(float4*)&a[4] = *(const float4*)&sA[k][ty*8+4];
            *(float4*)&b[0] = *(const float4*)&sB[k][tx*8];
            *(float4*)&b[4] = *(const float4*)&sB[k][tx*8+4];
            #pragma unroll
            for (int m = 0; m < 8; ++m)
                #pragma unroll
                for (int n = 0; n < 8; ++n) acc[m][n] += a[m]*b[n];
        }
        __syncthreads();
    }
    float* outp = T + ((size_t)(b*J_ + j)*DIM)*K_;
    #pragma unroll
    for (int m = 0; m < 8; ++m) {
        int i = ty*8 + m;
        *(float4*)&outp[(size_t)i*K_ + tx*8]   = make_float4(acc[m][0],acc[m][1],acc[m][2],acc[m][3]);
        *(float4*)&outp[(size_t)i*K_ + tx*8+4] = make_float4(acc[m][4],acc[m][5],acc[m][6],acc[m][7]);
    }
}

// ---------------------------------------------------------------------------
// y[b][o][k] += sum_i Wt[j][i][o] * T[b][j][i][k]   (atomic over j)
// grid (16 b, 16 j), 256 threads
__global__ __launch_bounds__(256) void k_mix2(
    const float* __restrict__ Wt, const float* __restrict__ T,
    float* __restrict__ y)
{
    __shared__ float sA[32][132];  // [i][o]
    __shared__ float sB[32][132];  // [i][k]
    const int t = threadIdx.x;
    const int tx = t & 15, ty = t >> 4;
    const int b = blockIdx.x, j = blockIdx.y;
    const float* wj = Wt + (size_t)j*DIM*DIM;
    const float* tb = T + ((size_t)(b*J_ + j)*DIM)*K_;

    float acc[8][8];
    #pragma unroll
    for (int m = 0; m < 8; ++m)
        #pragma unroll
        for (int n = 0; n < 8; ++n) acc[m][n] = 0.f;

    for (int i0 = 0; i0 < DIM; i0 += 32) {
        #pragma unroll
        for (int it = 0; it < 4; ++it) {   // Wt: 32 i x 128 o, direct
            int idx = t + it*256;
            int row = idx >> 5, col = (idx & 31) << 2;
            *(float4*)&sA[row][col] =
                *(const float4*)(wj + (size_t)(i0+row)*DIM + col);
        }
        #pragma unroll
        for (int it = 0; it < 4; ++it) {   // T: 32 i x 128 k, direct
            int idx = t + it*256;
            int row = idx >> 5, col = (idx & 31) << 2;
            *(float4*)&sB[row][col] =
                *(const float4*)(tb + (size_t)(i0+row)*K_ + col);
        }
        __syncthreads();
        #pragma unroll
        for (int k = 0; k < 32; ++k) {
            float a[8], b[8];
            *(float4*)&a[0] = *(const float4*)&sA[k][ty*8];
            *(float4*)&a[4] = *(const float4*)&sA[k][ty*8+4];
            *(float4*)&b[0] = *(const float4*)&sB[k][tx*8];
            *(float4*)&b[4] = *(const float4*)&sB[k][tx*8+4];
            #pragma unroll
            for (int m = 0; m < 8; ++m)
                #pragma unroll
                for (int n = 0; n < 8; ++n) acc[m][n] += a[m]*b[n];
        }
        __syncthreads();
    }
    #pragma unroll
    for (int m = 0; m < 8; ++m) {
        int o = ty*8 + m;
        #pragma unroll
        for (int n = 0; n < 8; ++n)
            atomicAdd(&y[((size_t)b*DIM + o)*K_ + tx*8 + n], acc[m][n]);
    }
}

// ---------------------------------------------------------------------------
// out[bo][p] = sum_k y[bo][k] * bases[p][k]
// grid (16 bo-tiles, 128 p-tiles), 256 threads
__global__ __launch_bounds__(256) void k_out(
    const float* __restrict__ y, const float* __restrict__ bases,
    float* __restrict__ out)
{
    __shared__ float sA[32][132];  // [k][bo]
    __shared__ float sB[32][132];  // [k][p]
    const int t = threadIdx.x;
    const int tx = t & 15, ty = t >> 4;
    const int bo0 = blockIdx.x * 128;
    const int p0  = blockIdx.y * 128;

    float acc[8][8];
    #pragma unroll
    for (int m = 0; m < 8; ++m)
        #pragma unroll
        for (int n = 0; n < 8; ++n) acc[m][n] = 0.f;

    for (int k0 = 0; k0 < K_; k0 += 32) {
        #pragma unroll
        for (int it = 0; it < 4; ++it) {   // y: 128 bo x 32 k, transpose
            int idx = t + it*256;
            int row = idx >> 3, col = (idx & 7) << 2;
            float4 v = *(const float4*)(y + (size_t)(bo0+row)*K_ + k0 + col);
            sA[col+0][row] = v.x; sA[col+1][row] = v.y;
            sA[col+2][row] = v.z; sA[col+3][row] = v.w;
        }
        #pragma unroll
        for (int it = 0; it < 4; ++it) {   // bases: 128 p x 32 k, transpose
            int idx = t + it*256;
            int row = idx >> 3, col = (idx & 7) << 2;
            float4 v = *(const float4*)(bases + (size_t)(p0+row)*K_ + k0 + col);
            sB[col+0][row] = v.x; sB[col+1][row] = v.y;
            sB[col+2][row] = v.z; sB[col+3][row] = v.w;
        }
        __syncthreads();
        #pragma unroll
        for (int k = 0; k < 32; ++k) {
            float a[8], b[8];
            *(float4*)&a[0] = *(const float4*)&sA[k][ty*8];
            *(float4*)&a[4] = *(const float4*)&sA[k][ty*8+4];
            *(float4*)&b[0] = *(const float4*)&sB[k][tx*8];
            *(float4*)&b[4] = *(const float4*)&sB[k][tx*8+4];
            #pragma unroll
            for (int m = 0; m < 8; ++m)
                #pragma unroll
                for (int n = 0; n < 8; ++n) acc[m][n] += a[m]*b[n];
        }
        __syncthreads();
    }
    #pragma unroll
    for (int m = 0; m < 8; ++m) {
        size_t row = bo0 + ty*8 + m;
        *(float4*)&out[row*NPTS + p0 + tx*8]   = make_float4(acc[m][0],acc[m][1],acc[m][2],acc[m][3]);
        *(float4*)&out[row*NPTS + p0 + tx*8+4] = make_float4(acc[m][4],acc[m][5],acc[m][6],acc[m][7]);
    }
}

// ---------------------------------------------------------------------------
extern "C" void kernel_launch(void* const* d_in, const int* in_sizes, int n_in,
                              void* d_out, int out_size, void* d_ws, size_t ws_size,
                              hipStream_t stream) {
    (void)in_sizes; (void)n_in; (void)out_size; (void)ws_size;
    const float* x       = (const float*)d_in[0];
    const float* bases   = (const float*)d_in[1];
    const float* wbases  = (const float*)d_in[2];
    const float* product = (const float*)d_in[3];
    const float* Do      = (const float*)d_in[4];
    const float* Di      = (const float*)d_in[5];
    const float* A       = (const float*)d_in[6];
    const float* Bm      = (const float*)d_in[7];
    const float* W       = (const float*)d_in[8];

    float* ws   = (float*)d_ws;
    float* xhat = ws + OFF_XHAT;
    float* Ht   = ws + OFF_HT;
    float* Wt   = ws + OFF_WT;
    float* T    = ws + OFF_T;
    float* y    = ws + OFF_Y;

    hipMemsetAsync(xhat, 0, (size_t)2048*128*sizeof(float), stream);
    hipMemsetAsync(y,    0, (size_t)2048*128*sizeof(float), stream);

    k_prep<<<4096, 128, 0, stream>>>(product, Do, Di, A, Bm, W, Ht, Wt);
    k_xhat<<<dim3(16, 32), 256, 0, stream>>>(x, wbases, xhat);
    k_mix1<<<dim3(16, 16), 256, 0, stream>>>(xhat, Ht, T);
    k_mix2<<<dim3(16, 16), 256, 0, stream>>>(Wt, T, y);
    k_out <<<dim3(16, 128), 256, 0, stream>>>(y, bases, (float*)d_out);
}

// Round 2
// 317.514 us; speedup vs baseline: 2.4060x; 2.4060x over previous
//
#include <hip/hip_runtime.h>

// Problem constants
#define B_    16
#define DIM   128
#define NPTS  16384
#define J_    16
#define K_    128
#define L_    128
#define R_    8
#define M1_   64

typedef float  f32x4 __attribute__((ext_vector_type(4)));
typedef short  s16x8 __attribute__((ext_vector_type(8)));
typedef unsigned short u16;
typedef u16 u16x8 __attribute__((ext_vector_type(8)));
typedef u16 u16x4 __attribute__((ext_vector_type(4)));

__device__ __forceinline__ u16 f2bf(float f) {
    unsigned u = __float_as_uint(f);
    u += 0x7FFFu + ((u >> 16) & 1u);          // round-nearest-even
    return (u16)(u >> 16);
}
#define MFMA16(a,b,c) __builtin_amdgcn_mfma_f32_16x16x32_bf16((a),(b),(c),0,0,0)

// Workspace byte offsets (total 18 MB; known-safe <= 21 MB)
#define OFF_R0   0u            // 8 MB: stageA partials f32 [8][2048][128]; later Tt u16 [16][128][2048]
#define OFF_R1   8388608u      // 4 MB: wbT u16 [128][16384]; later basesb u16 [16384][128]
#define OFF_HKL  12582912u     // 0.5 MB: Hkl u16 [16][128][128]  ([j][k][l], l-contig)
#define OFF_W2T  13107200u     // 0.5 MB: W2T u16 [128][2048]     ([o][j*128+i], ji-contig)
#define OFF_XHB  13631488u     // 0.5 MB: xhatb u16 [2048][128]   ([b*128+i][l], l-contig)
#define OFF_YB   14155776u     // 0.5 MB: yb u16 [2048][128]      ([b*128+o][k], k-contig)
#define OFF_YP   14680064u     // 4 MB: ypart f32 [4][16][128][128]

// ---------------------------------------------------------------------------
// Hkl[j][k][l] = D_out[j,k]*D_in[j,l]*product[k,l] + Q[j,k,l] (k,l<64), bf16
// W2T[o][j*128+i] = weights[i][o][j], bf16
__global__ __launch_bounds__(128) void k_prep(
    const float* __restrict__ product, const float* __restrict__ Do,
    const float* __restrict__ Di, const float* __restrict__ A,
    const float* __restrict__ Bm, const float* __restrict__ W,
    u16* __restrict__ Hkl, u16* __restrict__ W2T)
{
    int bid = blockIdx.x, t = threadIdx.x;
    if (bid < 2048) {
        int j = bid >> 7, k = bid & 127, l = t;
        float v = Do[j*K_ + k] * Di[j*L_ + l] * product[k*L_ + l];
        if (k < M1_ && l < M1_) {
            float q = 0.f;
            #pragma unroll
            for (int r = 0; r < R_; ++r)
                q += A[(j*R_ + r)*M1_ + k] * Bm[(j*R_ + r)*M1_ + l];
            v += q;
        }
        Hkl[j*16384 + k*128 + l] = f2bf(v);
    } else {
        int idx = (bid - 2048)*128 + t;          // 0..262143
        int o = idx >> 11, ji = idx & 2047, j = ji >> 7, i = ji & 127;
        W2T[idx] = f2bf(W[(i*DIM + o)*J_ + j]);
    }
}

// ---------------------------------------------------------------------------
// wbT[l][p] = bf16(wbases[p][l])   (tiled transpose through LDS)
__global__ __launch_bounds__(256) void k_wbT(
    const float* __restrict__ wb, u16* __restrict__ wbT)
{
    __shared__ u16 sT[128][136];
    const int t = threadIdx.x, p0 = blockIdx.x * 128;
    #pragma unroll
    for (int it = 0; it < 16; ++it) {
        int idx = it*256 + t, row = idx >> 5, c4 = (idx & 31) * 4;
        float4 v = *(const float4*)(wb + (size_t)(p0+row)*L_ + c4);
        sT[c4+0][row] = f2bf(v.x); sT[c4+1][row] = f2bf(v.y);
        sT[c4+2][row] = f2bf(v.z); sT[c4+3][row] = f2bf(v.w);
    }
    __syncthreads();
    #pragma unroll
    for (int it = 0; it < 8; ++it) {
        int idx = it*256 + t, l = idx >> 4, pc = (idx & 15) * 8;
        *(u16x8*)(wbT + (size_t)l*NPTS + p0 + pc) = *(const u16x8*)&sT[l][pc];
    }
}

// ---------------------------------------------------------------------------
// plain f32 -> bf16 stream convert (for bases)
__global__ __launch_bounds__(256) void k_cvt(
    const float* __restrict__ s, u16* __restrict__ d)
{
    int i = (blockIdx.x*256 + threadIdx.x) * 4;
    float4 v = *(const float4*)(s + i);
    u16x4 o = { f2bf(v.x), f2bf(v.y), f2bf(v.z), f2bf(v.w) };
    *(u16x4*)(d + i) = o;
}

// ---------------------------------------------------------------------------
// Stage A: part[ks][bi][l] = sum_{p in chunk} x[bi][p]*wbT[l][p]
// grid (32 m-tiles of 64 rows, 8 k-splits of 2048), 512 threads (8 waves, 2x4,
// wave-tile 32x32). Fused f32->bf16 convert in A staging.
__global__ __launch_bounds__(512) void k_stageA(
    const float* __restrict__ x, const u16* __restrict__ wbT,
    float* __restrict__ part)
{
    __shared__ u16 sA[64][72];    // [m][p] bf16, pad 8
    __shared__ u16 sB[128][72];   // [l][p] bf16
    const int t = threadIdx.x, lane = t & 63, wave = t >> 6;
    const int quad = lane >> 4, l16 = lane & 15;
    const int wr = wave >> 2, wc = wave & 3;
    const int m0 = blockIdx.x * 64;
    const size_t pbase = (size_t)blockIdx.y * 2048;

    f32x4 acc[2][2] = {};
    const int ac4 = (t & 15) * 4, arr = t >> 4;    // A staging: 2 float4/thread
    const int bc8 = (t & 7) * 8,  brr = t >> 3;    // B staging: 2 x 16B/thread

    for (int pc = 0; pc < 2048; pc += 64) {
        #pragma unroll
        for (int i = 0; i < 2; ++i) {
            int row = arr + 32*i;
            float4 v = *(const float4*)(x + (size_t)(m0+row)*NPTS + pbase + pc + ac4);
            u16x4 h = { f2bf(v.x), f2bf(v.y), f2bf(v.z), f2bf(v.w) };
            *(u16x4*)&sA[row][ac4] = h;
        }
        #pragma unroll
        for (int i = 0; i < 2; ++i) {
            int row = brr + 64*i;
            *(u16x8*)&sB[row][bc8] =
                *(const u16x8*)(wbT + (size_t)row*NPTS + pbase + pc + bc8);
        }
        __syncthreads();
        #pragma unroll
        for (int ks = 0; ks < 2; ++ks) {
            int kb = ks*32 + quad*8;
            s16x8 a0 = *(const s16x8*)&sA[wr*32      + l16][kb];
            s16x8 a1 = *(const s16x8*)&sA[wr*32 + 16 + l16][kb];
            s16x8 b0 = *(const s16x8*)&sB[wc*32      + l16][kb];
            s16x8 b1 = *(const s16x8*)&sB[wc*32 + 16 + l16][kb];
            acc[0][0] = MFMA16(a0, b0, acc[0][0]);
            acc[0][1] = MFMA16(a0, b1, acc[0][1]);
            acc[1][0] = MFMA16(a1, b0, acc[1][0]);
            acc[1][1] = MFMA16(a1, b1, acc[1][1]);
        }
        __syncthreads();
    }
    float* po = part + (size_t)blockIdx.y * (2048*128);
    #pragma unroll
    for (int mt = 0; mt < 2; ++mt)
      #pragma unroll
      for (int r = 0; r < 4; ++r) {
        int row = m0 + wr*32 + mt*16 + quad*4 + r;
        #pragma unroll
        for (int nt = 0; nt < 2; ++nt) {
            int col = wc*32 + nt*16 + l16;
            po[(size_t)row*128 + col] = acc[mt][nt][r];
        }
      }
}

// xhatb[bi][l] = bf16( sum of 8 partials )
__global__ __launch_bounds__(256) void k_reduceA(
    const float* __restrict__ part, u16* __restrict__ xhatb)
{
    int i = blockIdx.x * 1024 + threadIdx.x;
    #pragma unroll
    for (int e = 0; e < 4; ++e, i += 256) {
        float s = 0.f;
        #pragma unroll
        for (int p = 0; p < 8; ++p) s += part[p*262144 + i];
        xhatb[i] = f2bf(s);
    }
}

// ---------------------------------------------------------------------------
// mix1: Tt[b][k][j*128+i] = sum_l Hkl[j][k][l] * xhatb[b*128+i][l]
// grid (16 b, 16 j), 256 threads (4 waves 2x2, wave-tile 64x64), single-shot K=128
__global__ __launch_bounds__(256) void k_mix1(
    const u16* __restrict__ Hkl, const u16* __restrict__ xhatb,
    u16* __restrict__ Tt)
{
    __shared__ u16 sA[128][136];   // [k][l]
    __shared__ u16 sB[128][136];   // [i][l]
    const int t = threadIdx.x, lane = t & 63, wave = t >> 6;
    const int quad = lane >> 4, l16 = lane & 15;
    const int wr = wave >> 1, wc = wave & 1;
    const int b = blockIdx.x, j = blockIdx.y;
    const u16* ha = Hkl + j*16384;
    const u16* xb = xhatb + b*16384;

    const int c8 = (t & 15)*8, rr = t >> 4;
    #pragma unroll
    for (int i = 0; i < 8; ++i) {
        int row = rr + 16*i;
        *(u16x8*)&sA[row][c8] = *(const u16x8*)(ha + row*128 + c8);
        *(u16x8*)&sB[row][c8] = *(const u16x8*)(xb + row*128 + c8);
    }
    __syncthreads();

    f32x4 acc[4][4] = {};
    #pragma unroll
    for (int ks = 0; ks < 4; ++ks) {
        int kb = ks*32 + quad*8;
        s16x8 a[4], bf[4];
        #pragma unroll
        for (int mt = 0; mt < 4; ++mt) a[mt]  = *(const s16x8*)&sA[wr*64 + mt*16 + l16][kb];
        #pragma unroll
        for (int nt = 0; nt < 4; ++nt) bf[nt] = *(const s16x8*)&sB[wc*64 + nt*16 + l16][kb];
        #pragma unroll
        for (int mt = 0; mt < 4; ++mt)
            #pragma unroll
            for (int nt = 0; nt < 4; ++nt)
                acc[mt][nt] = MFMA16(a[mt], bf[nt], acc[mt][nt]);
    }
    u16* to = Tt + (size_t)b*262144 + (j << 7);
    #pragma unroll
    for (int mt = 0; mt < 4; ++mt)
      #pragma unroll
      for (int r = 0; r < 4; ++r) {
        int k = wr*64 + mt*16 + quad*4 + r;
        #pragma unroll
        for (int nt = 0; nt < 4; ++nt) {
            int i = wc*64 + nt*16 + l16;
            to[(size_t)k*2048 + i] = f2bf(acc[mt][nt][r]);
        }
      }
}

// ---------------------------------------------------------------------------
// mix2: ypart[js][b][o][k] = sum_{ji in chunk} W2T[o][ji] * Tt[b][k][ji]
// grid (16 b, 4 js of 512), 256 threads (2x2 waves, wave-tile 64x64)
__global__ __launch_bounds__(256) void k_mix2(
    const u16* __restrict__ W2T, const u16* __restrict__ Tt,
    float* __restrict__ ypart)
{
    __shared__ u16 sA[128][72];    // [o][ji]
    __shared__ u16 sB[128][72];    // [k][ji]
    const int t = threadIdx.x, lane = t & 63, wave = t >> 6;
    const int quad = lane >> 4, l16 = lane & 15;
    const int wr = wave >> 1, wc = wave & 1;
    const int b = blockIdx.x, js = blockIdx.y;
    const int ji0 = js * 512;
    const u16* tb = Tt + (size_t)b*262144;

    f32x4 acc[4][4] = {};
    const int c8 = (t & 7)*8, rr = t >> 3;
    for (int pc = 0; pc < 512; pc += 64) {
        #pragma unroll
        for (int i = 0; i < 4; ++i) {
            int row = rr + 32*i;
            *(u16x8*)&sA[row][c8] = *(const u16x8*)(W2T + (size_t)row*2048 + ji0 + pc + c8);
            *(u16x8*)&sB[row][c8] = *(const u16x8*)(tb  + (size_t)row*2048 + ji0 + pc + c8);
        }
        __syncthreads();
        #pragma unroll
        for (int ks = 0; ks < 2; ++ks) {
            int kb = ks*32 + quad*8;
            s16x8 a[4], bf[4];
            #pragma unroll
            for (int mt = 0; mt < 4; ++mt) a[mt]  = *(const s16x8*)&sA[wr*64 + mt*16 + l16][kb];
            #pragma unroll
            for (int nt = 0; nt < 4; ++nt) bf[nt] = *(const s16x8*)&sB[wc*64 + nt*16 + l16][kb];
            #pragma unroll
            for (int mt = 0; mt < 4; ++mt)
                #pragma unroll
                for (int nt = 0; nt < 4; ++nt)
                    acc[mt][nt] = MFMA16(a[mt], bf[nt], acc[mt][nt]);
        }
        __syncthreads();
    }
    float* yo = ypart + ((size_t)(js*16 + b) << 14);
    #pragma unroll
    for (int mt = 0; mt < 4; ++mt)
      #pragma unroll
      for (int r = 0; r < 4; ++r) {
        int o = wr*64 + mt*16 + quad*4 + r;
        #pragma unroll
        for (int nt = 0; nt < 4; ++nt) {
            int k = wc*64 + nt*16 + l16;
            yo[(size_t)o*128 + k] = acc[mt][nt][r];
        }
      }
}

// yb[bo][k] = bf16( sum of 4 partials )
__global__ __launch_bounds__(256) void k_reduceY(
    const float* __restrict__ part, u16* __restrict__ yb)
{
    int i = blockIdx.x * 1024 + threadIdx.x;
    #pragma unroll
    for (int e = 0; e < 4; ++e, i += 256) {
        float s = part[i] + part[262144 + i] + part[2*262144 + i] + part[3*262144 + i];
        yb[i] = f2bf(s);
    }
}

// ---------------------------------------------------------------------------
// Stage E: out[bo][p] = sum_k yb[bo][k] * basesb[p][k]
// grid (16 bo-tiles, 128 p-tiles), 256 threads, single-shot K=128
__global__ __launch_bounds__(256) void k_stageE(
    const u16* __restrict__ yb, const u16* __restrict__ basesb,
    float* __restrict__ out)
{
    __shared__ u16 sA[128][136];   // [bo][k]
    __shared__ u16 sB[128][136];   // [p][k]
    const int t = threadIdx.x, lane = t & 63, wave = t >> 6;
    const int quad = lane >> 4, l16 = lane & 15;
    const int wr = wave >> 1, wc = wave & 1;
    const int bo0 = blockIdx.x * 128, p0 = blockIdx.y * 128;

    const int c8 = (t & 15)*8, rr = t >> 4;
    #pragma unroll
    for (int i = 0; i < 8; ++i) {
        int row = rr + 16*i;
        *(u16x8*)&sA[row][c8] = *(const u16x8*)(yb     + (size_t)(bo0+row)*128 + c8);
        *(u16x8*)&sB[row][c8] = *(const u16x8*)(basesb + (size_t)(p0 +row)*128 + c8);
    }
    __syncthreads();

    f32x4 acc[4][4] = {};
    #pragma unroll
    for (int ks = 0; ks < 4; ++ks) {
        int kb = ks*32 + quad*8;
        s16x8 a[4], bf[4];
        #pragma unroll
        for (int mt = 0; mt < 4; ++mt) a[mt]  = *(const s16x8*)&sA[wr*64 + mt*16 + l16][kb];
        #pragma unroll
        for (int nt = 0; nt < 4; ++nt) bf[nt] = *(const s16x8*)&sB[wc*64 + nt*16 + l16][kb];
        #pragma unroll
        for (int mt = 0; mt < 4; ++mt)
            #pragma unroll
            for (int nt = 0; nt < 4; ++nt)
                acc[mt][nt] = MFMA16(a[mt], bf[nt], acc[mt][nt]);
    }
    #pragma unroll
    for (int mt = 0; mt < 4; ++mt)
      #pragma unroll
      for (int r = 0; r < 4; ++r) {
        size_t row = bo0 + wr*64 + mt*16 + quad*4 + r;
        #pragma unroll
        for (int nt = 0; nt < 4; ++nt) {
            int p = p0 + wc*64 + nt*16 + l16;
            out[row*NPTS + p] = acc[mt][nt][r];
        }
      }
}

// ---------------------------------------------------------------------------
extern "C" void kernel_launch(void* const* d_in, const int* in_sizes, int n_in,
                              void* d_out, int out_size, void* d_ws, size_t ws_size,
                              hipStream_t stream) {
    (void)in_sizes; (void)n_in; (void)out_size; (void)ws_size;
    const float* x       = (const float*)d_in[0];
    const float* bases   = (const float*)d_in[1];
    const float* wbases  = (const float*)d_in[2];
    const float* product = (const float*)d_in[3];
    const float* Do      = (const float*)d_in[4];
    const float* Di      = (const float*)d_in[5];
    const float* A       = (const float*)d_in[6];
    const float* Bm      = (const float*)d_in[7];
    const float* W       = (const float*)d_in[8];

    char* ws = (char*)d_ws;
    float* partA  = (float*)(ws + OFF_R0);
    u16*   Tt     = (u16*)  (ws + OFF_R0);   // reuses partA region after reduceA
    u16*   wbT    = (u16*)  (ws + OFF_R1);
    u16*   basesb = (u16*)  (ws + OFF_R1);   // reuses wbT region after stageA
    u16*   Hkl    = (u16*)  (ws + OFF_HKL);
    u16*   W2T    = (u16*)  (ws + OFF_W2T);
    u16*   xhatb  = (u16*)  (ws + OFF_XHB);
    u16*   yb     = (u16*)  (ws + OFF_YB);
    float* ypart  = (float*)(ws + OFF_YP);

    k_prep   <<<4096, 128, 0, stream>>>(product, Do, Di, A, Bm, W, Hkl, W2T);
    k_wbT    <<<128, 256, 0, stream>>>(wbases, wbT);
    k_stageA <<<dim3(32, 8), 512, 0, stream>>>(x, wbT, partA);
    k_reduceA<<<256, 256, 0, stream>>>(partA, xhatb);
    k_cvt    <<<2048, 256, 0, stream>>>(bases, basesb);   // after stageA: reuses wbT region
    k_mix1   <<<dim3(16, 16), 256, 0, stream>>>(Hkl, xhatb, Tt);
    k_mix2   <<<dim3(16, 4), 256, 0, stream>>>(W2T, Tt, ypart);
    k_reduceY<<<256, 256, 0, stream>>>(ypart, yb);
    k_stageE <<<dim3(16, 128), 256, 0, stream>>>(yb, basesb, (float*)d_out);
}

// Round 3
// 315.599 us; speedup vs baseline: 2.4206x; 1.0061x over previous
//
#include <hip/hip_runtime.h>

// Problem constants
#define B_    16
#define DIM   128
#define NPTS  16384
#define J_    16
#define K_    128
#define L_    128
#define R_    8
#define M1_   64

typedef float  f32x4 __attribute__((ext_vector_type(4)));
typedef short  s16x8 __attribute__((ext_vector_type(8)));
typedef unsigned short u16;
typedef u16 u16x8 __attribute__((ext_vector_type(8)));
typedef u16 u16x4 __attribute__((ext_vector_type(4)));

__device__ __forceinline__ u16 f2bf(float f) {
    unsigned u = __float_as_uint(f);
    u += 0x7FFFu + ((u >> 16) & 1u);          // round-nearest-even
    return (u16)(u >> 16);
}
#define MFMA16(a,b,c) __builtin_amdgcn_mfma_f32_16x16x32_bf16((a),(b),(c),0,0,0)

// Workspace byte offsets (34 MB total; ws is >=512 MB per harness fill size)
#define OFF_PARTA 0u           // 8 MB: stageA partials f32 [8][2048][128]; reused as Tt u16 [16][128][2048]
#define OFF_WBT   8388608u     // 4 MB: wbT u16 [128][16384]
#define OFF_BASB  12582912u    // 4 MB: basesb u16 [16384][128]
#define OFF_HKL   16777216u    // 0.5 MB: Hkl u16 [16][128][128]   ([j][k][l])
#define OFF_W2T   17301504u    // 0.5 MB: W2T u16 [128][2048]      ([o][j*128+i])
#define OFF_XHB   17825792u    // 0.5 MB: xhatb u16 [2048][128]
#define OFF_YB    18350080u    // 0.5 MB: yb u16 [2048][128]
#define OFF_YP    18874368u    // 16 MB: ypart f32 [16][16][128][128]

// ---------------------------------------------------------------------------
// Merged prep: one launch, range-dispatched by blockIdx (uniform per block).
//  [0,1024):     Hkl[j][k][l] = Do*Di*product + lowrank Q
//  [1024,2048):  W2T[o][j*128+i] = weights[i][o][j]
//  [2048,2176):  wbT[l][p] = bf16(wbases[p][l])   (LDS transpose)
//  [2176,4224):  basesb = bf16(bases)
__global__ __launch_bounds__(256) void k_prep(
    const float* __restrict__ product, const float* __restrict__ Do,
    const float* __restrict__ Di, const float* __restrict__ A,
    const float* __restrict__ Bm, const float* __restrict__ W,
    const float* __restrict__ wb, const float* __restrict__ bases,
    u16* __restrict__ Hkl, u16* __restrict__ W2T,
    u16* __restrict__ wbT, u16* __restrict__ basesb)
{
    __shared__ u16 sT[128][136];
    const int bid = blockIdx.x, t = threadIdx.x;
    if (bid < 1024) {
        int idx = (bid << 8) | t;
        int j = idx >> 14, k = (idx >> 7) & 127, l = idx & 127;
        float v = Do[j*K_ + k] * Di[j*L_ + l] * product[k*L_ + l];
        if (k < M1_ && l < M1_) {
            float q = 0.f;
            #pragma unroll
            for (int r = 0; r < R_; ++r)
                q += A[(j*R_ + r)*M1_ + k] * Bm[(j*R_ + r)*M1_ + l];
            v += q;
        }
        Hkl[idx] = f2bf(v);
    } else if (bid < 2048) {
        int idx = ((bid - 1024) << 8) | t;
        int o = idx >> 11, ji = idx & 2047, j = ji >> 7, i = ji & 127;
        W2T[idx] = f2bf(W[(i*DIM + o)*J_ + j]);
    } else if (bid < 2176) {
        const int p0 = (bid - 2048) * 128;
        #pragma unroll
        for (int it = 0; it < 16; ++it) {
            int idx = it*256 + t, row = idx >> 5, c4 = (idx & 31) * 4;
            float4 v = *(const float4*)(wb + (size_t)(p0+row)*L_ + c4);
            sT[c4+0][row] = f2bf(v.x); sT[c4+1][row] = f2bf(v.y);
            sT[c4+2][row] = f2bf(v.z); sT[c4+3][row] = f2bf(v.w);
        }
        __syncthreads();
        #pragma unroll
        for (int it = 0; it < 8; ++it) {
            int idx = it*256 + t, l = idx >> 4, pc = (idx & 15) * 8;
            *(u16x8*)(wbT + (size_t)l*NPTS + p0 + pc) = *(const u16x8*)&sT[l][pc];
        }
    } else {
        int i = (((bid - 2176) << 8) | t) * 4;
        float4 v = *(const float4*)(bases + i);
        u16x4 o4 = { f2bf(v.x), f2bf(v.y), f2bf(v.z), f2bf(v.w) };
        *(u16x4*)(basesb + i) = o4;
    }
}

// ---------------------------------------------------------------------------
// Stage A: part[ks][bi][l] = sum_{p in 2048-chunk} x[bi][p]*wbT[l][p]
// grid (32 m-tiles of 64, 8 k-splits), 512 thr (8 waves 2x4, wave-tile 32x32),
// BK=128 (16 MFMA per barrier pair, 16 chunks).
__global__ __launch_bounds__(512) void k_stageA(
    const float* __restrict__ x, const u16* __restrict__ wbT,
    float* __restrict__ part)
{
    __shared__ u16 sA[64][136];    // [m][p]
    __shared__ u16 sB[128][136];   // [l][p]
    const int t = threadIdx.x, lane = t & 63, wave = t >> 6;
    const int quad = lane >> 4, l16 = lane & 15;
    const int wr = wave >> 2, wc = wave & 3;
    const int m0 = blockIdx.x * 64;
    const size_t pbase = (size_t)blockIdx.y * 2048;

    f32x4 acc[2][2] = {};
    const int ac4 = (t & 31) * 4, arr = t >> 5;    // x: 4 float4/thread
    const int bc8 = (t & 15) * 8, brr = t >> 4;    // wbT: 4 u16x8/thread

    for (int pc = 0; pc < 2048; pc += 128) {
        #pragma unroll
        for (int i = 0; i < 4; ++i) {
            int row = arr + 16*i;
            float4 v = *(const float4*)(x + (size_t)(m0+row)*NPTS + pbase + pc + ac4);
            u16x4 h = { f2bf(v.x), f2bf(v.y), f2bf(v.z), f2bf(v.w) };
            *(u16x4*)&sA[row][ac4] = h;
        }
        #pragma unroll
        for (int i = 0; i < 4; ++i) {
            int row = brr + 32*i;
            *(u16x8*)&sB[row][bc8] =
                *(const u16x8*)(wbT + (size_t)row*NPTS + pbase + pc + bc8);
        }
        __syncthreads();
        #pragma unroll
        for (int ks = 0; ks < 4; ++ks) {
            int kb = ks*32 + quad*8;
            s16x8 a0 = *(const s16x8*)&sA[wr*32      + l16][kb];
            s16x8 a1 = *(const s16x8*)&sA[wr*32 + 16 + l16][kb];
            s16x8 b0 = *(const s16x8*)&sB[wc*32      + l16][kb];
            s16x8 b1 = *(const s16x8*)&sB[wc*32 + 16 + l16][kb];
            acc[0][0] = MFMA16(a0, b0, acc[0][0]);
            acc[0][1] = MFMA16(a0, b1, acc[0][1]);
            acc[1][0] = MFMA16(a1, b0, acc[1][0]);
            acc[1][1] = MFMA16(a1, b1, acc[1][1]);
        }
        __syncthreads();
    }
    float* po = part + (size_t)blockIdx.y * (2048*128);
    #pragma unroll
    for (int mt = 0; mt < 2; ++mt)
      #pragma unroll
      for (int r = 0; r < 4; ++r) {
        int row = m0 + wr*32 + mt*16 + quad*4 + r;
        #pragma unroll
        for (int nt = 0; nt < 2; ++nt) {
            int col = wc*32 + nt*16 + l16;
            po[(size_t)row*128 + col] = acc[mt][nt][r];
        }
      }
}

// xhatb[bi][l] = bf16( sum of 8 partials )
__global__ __launch_bounds__(256) void k_reduceA(
    const float* __restrict__ part, u16* __restrict__ xhatb)
{
    int i = blockIdx.x * 1024 + threadIdx.x;
    #pragma unroll
    for (int e = 0; e < 4; ++e, i += 256) {
        float s = 0.f;
        #pragma unroll
        for (int p = 0; p < 8; ++p) s += part[p*262144 + i];
        xhatb[i] = f2bf(s);
    }
}

// ---------------------------------------------------------------------------
// mix1: Tt[b][k][j*128+i] = sum_l Hkl[j][k][l] * xhatb[b*128+i][l]
// grid (16 b, 16 j), 256 thr (4 waves 2x2, wave-tile 64x64), single-shot K=128
__global__ __launch_bounds__(256) void k_mix1(
    const u16* __restrict__ Hkl, const u16* __restrict__ xhatb,
    u16* __restrict__ Tt)
{
    __shared__ u16 sA[128][136];   // [k][l]
    __shared__ u16 sB[128][136];   // [i][l]
    const int t = threadIdx.x, lane = t & 63, wave = t >> 6;
    const int quad = lane >> 4, l16 = lane & 15;
    const int wr = wave >> 1, wc = wave & 1;
    const int b = blockIdx.x, j = blockIdx.y;
    const u16* ha = Hkl + j*16384;
    const u16* xb = xhatb + b*16384;

    const int c8 = (t & 15)*8, rr = t >> 4;
    #pragma unroll
    for (int i = 0; i < 8; ++i) {
        int row = rr + 16*i;
        *(u16x8*)&sA[row][c8] = *(const u16x8*)(ha + row*128 + c8);
        *(u16x8*)&sB[row][c8] = *(const u16x8*)(xb + row*128 + c8);
    }
    __syncthreads();

    f32x4 acc[4][4] = {};
    #pragma unroll
    for (int ks = 0; ks < 4; ++ks) {
        int kb = ks*32 + quad*8;
        s16x8 a[4], bf[4];
        #pragma unroll
        for (int mt = 0; mt < 4; ++mt) a[mt]  = *(const s16x8*)&sA[wr*64 + mt*16 + l16][kb];
        #pragma unroll
        for (int nt = 0; nt < 4; ++nt) bf[nt] = *(const s16x8*)&sB[wc*64 + nt*16 + l16][kb];
        #pragma unroll
        for (int mt = 0; mt < 4; ++mt)
            #pragma unroll
            for (int nt = 0; nt < 4; ++nt)
                acc[mt][nt] = MFMA16(a[mt], bf[nt], acc[mt][nt]);
    }
    u16* to = Tt + (size_t)b*262144 + (j << 7);
    #pragma unroll
    for (int mt = 0; mt < 4; ++mt)
      #pragma unroll
      for (int r = 0; r < 4; ++r) {
        int k = wr*64 + mt*16 + quad*4 + r;
        #pragma unroll
        for (int nt = 0; nt < 4; ++nt) {
            int i = wc*64 + nt*16 + l16;
            to[(size_t)k*2048 + i] = f2bf(acc[mt][nt][r]);
        }
      }
}

// ---------------------------------------------------------------------------
// mix2: ypart[c][b][o][k] = sum_{ji in 128-chunk c} W2T[o][ji] * Tt[b][k][ji]
// grid (16 b, 16 c), 256 thr (2x2 waves, wave-tile 64x64), single-shot 128
__global__ __launch_bounds__(256) void k_mix2(
    const u16* __restrict__ W2T, const u16* __restrict__ Tt,
    float* __restrict__ ypart)
{
    __shared__ u16 sA[128][136];   // [o][ji]
    __shared__ u16 sB[128][136];   // [k][ji]
    const int t = threadIdx.x, lane = t & 63, wave = t >> 6;
    const int quad = lane >> 4, l16 = lane & 15;
    const int wr = wave >> 1, wc = wave & 1;
    const int b = blockIdx.x, c = blockIdx.y;
    const int ji0 = c * 128;
    const u16* tb = Tt + (size_t)b*262144;

    const int c8 = (t & 15)*8, rr = t >> 4;
    #pragma unroll
    for (int i = 0; i < 8; ++i) {
        int row = rr + 16*i;
        *(u16x8*)&sA[row][c8] = *(const u16x8*)(W2T + (size_t)row*2048 + ji0 + c8);
        *(u16x8*)&sB[row][c8] = *(const u16x8*)(tb  + (size_t)row*2048 + ji0 + c8);
    }
    __syncthreads();

    f32x4 acc[4][4] = {};
    #pragma unroll
    for (int ks = 0; ks < 4; ++ks) {
        int kb = ks*32 + quad*8;
        s16x8 a[4], bf[4];
        #pragma unroll
        for (int mt = 0; mt < 4; ++mt) a[mt]  = *(const s16x8*)&sA[wr*64 + mt*16 + l16][kb];
        #pragma unroll
        for (int nt = 0; nt < 4; ++nt) bf[nt] = *(const s16x8*)&sB[wc*64 + nt*16 + l16][kb];
        #pragma unroll
        for (int mt = 0; mt < 4; ++mt)
            #pragma unroll
            for (int nt = 0; nt < 4; ++nt)
                acc[mt][nt] = MFMA16(a[mt], bf[nt], acc[mt][nt]);
    }
    float* yo = ypart + ((size_t)(c*16 + b) << 14);
    #pragma unroll
    for (int mt = 0; mt < 4; ++mt)
      #pragma unroll
      for (int r = 0; r < 4; ++r) {
        int o = wr*64 + mt*16 + quad*4 + r;
        #pragma unroll
        for (int nt = 0; nt < 4; ++nt) {
            int k = wc*64 + nt*16 + l16;
            yo[(size_t)o*128 + k] = acc[mt][nt][r];
        }
      }
}

// yb[bo][k] = bf16( sum of 16 partials )
__global__ __launch_bounds__(256) void k_reduceY(
    const float* __restrict__ part, u16* __restrict__ yb)
{
    int i = blockIdx.x * 1024 + threadIdx.x;
    #pragma unroll
    for (int e = 0; e < 4; ++e, i += 256) {
        float s = 0.f;
        #pragma unroll
        for (int p = 0; p < 16; ++p) s += part[p*262144 + i];
        yb[i] = f2bf(s);
    }
}

// ---------------------------------------------------------------------------
// Stage E: out[bo][p] = sum_k yb[bo][k] * basesb[p][k]
// grid (16 bo-tiles, 128 p-tiles), 256 thr, single-shot K=128
__global__ __launch_bounds__(256) void k_stageE(
    const u16* __restrict__ yb, const u16* __restrict__ basesb,
    float* __restrict__ out)
{
    __shared__ u16 sA[128][136];   // [bo][k]
    __shared__ u16 sB[128][136];   // [p][k]
    const int t = threadIdx.x, lane = t & 63, wave = t >> 6;
    const int quad = lane >> 4, l16 = lane & 15;
    const int wr = wave >> 1, wc = wave & 1;
    const int bo0 = blockIdx.x * 128, p0 = blockIdx.y * 128;

    const int c8 = (t & 15)*8, rr = t >> 4;
    #pragma unroll
    for (int i = 0; i < 8; ++i) {
        int row = rr + 16*i;
        *(u16x8*)&sA[row][c8] = *(const u16x8*)(yb     + (size_t)(bo0+row)*128 + c8);
        *(u16x8*)&sB[row][c8] = *(const u16x8*)(basesb + (size_t)(p0 +row)*128 + c8);
    }
    __syncthreads();

    f32x4 acc[4][4] = {};
    #pragma unroll
    for (int ks = 0; ks < 4; ++ks) {
        int kb = ks*32 + quad*8;
        s16x8 a[4], bf[4];
        #pragma unroll
        for (int mt = 0; mt < 4; ++mt) a[mt]  = *(const s16x8*)&sA[wr*64 + mt*16 + l16][kb];
        #pragma unroll
        for (int nt = 0; nt < 4; ++nt) bf[nt] = *(const s16x8*)&sB[wc*64 + nt*16 + l16][kb];
        #pragma unroll
        for (int mt = 0; mt < 4; ++mt)
            #pragma unroll
            for (int nt = 0; nt < 4; ++nt)
                acc[mt][nt] = MFMA16(a[mt], bf[nt], acc[mt][nt]);
    }
    #pragma unroll
    for (int mt = 0; mt < 4; ++mt)
      #pragma unroll
      for (int r = 0; r < 4; ++r) {
        size_t row = bo0 + wr*64 + mt*16 + quad*4 + r;
        #pragma unroll
        for (int nt = 0; nt < 4; ++nt) {
            int p = p0 + wc*64 + nt*16 + l16;
            out[row*NPTS + p] = acc[mt][nt][r];
        }
      }
}

// ---------------------------------------------------------------------------
extern "C" void kernel_launch(void* const* d_in, const int* in_sizes, int n_in,
                              void* d_out, int out_size, void* d_ws, size_t ws_size,
                              hipStream_t stream) {
    (void)in_sizes; (void)n_in; (void)out_size; (void)ws_size;
    const float* x       = (const float*)d_in[0];
    const float* bases   = (const float*)d_in[1];
    const float* wbases  = (const float*)d_in[2];
    const float* product = (const float*)d_in[3];
    const float* Do      = (const float*)d_in[4];
    const float* Di      = (const float*)d_in[5];
    const float* A       = (const float*)d_in[6];
    const float* Bm      = (const float*)d_in[7];
    const float* W       = (const float*)d_in[8];

    char* ws = (char*)d_ws;
    float* partA  = (float*)(ws + OFF_PARTA);
    u16*   Tt     = (u16*)  (ws + OFF_PARTA);   // reuses partA after reduceA
    u16*   wbT    = (u16*)  (ws + OFF_WBT);
    u16*   basesb = (u16*)  (ws + OFF_BASB);
    u16*   Hkl    = (u16*)  (ws + OFF_HKL);
    u16*   W2T    = (u16*)  (ws + OFF_W2T);
    u16*   xhatb  = (u16*)  (ws + OFF_XHB);
    u16*   yb     = (u16*)  (ws + OFF_YB);
    float* ypart  = (float*)(ws + OFF_YP);

    k_prep   <<<4224, 256, 0, stream>>>(product, Do, Di, A, Bm, W, wbases, bases,
                                        Hkl, W2T, wbT, basesb);
    k_stageA <<<dim3(32, 8), 512, 0, stream>>>(x, wbT, partA);
    k_reduceA<<<256, 256, 0, stream>>>(partA, xhatb);
    k_mix1   <<<dim3(16, 16), 256, 0, stream>>>(Hkl, xhatb, Tt);
    k_mix2   <<<dim3(16, 16), 256, 0, stream>>>(W2T, Tt, ypart);
    k_reduceY<<<256, 256, 0, stream>>>(ypart, yb);
    k_stageE <<<dim3(16, 128), 256, 0, stream>>>(yb, basesb, (float*)d_out);
}